// Round 10
// baseline (232.029 us; speedup 1.0000x reference)
//
#include <hip/hip_runtime.h>

#define N_NODES 100000
#define N_EDGES 1600000
#define D 64
#define NBUCK 391          // ceil(N_NODES/256) buckets of 256 dst
#define GBE 391            // edge-pass grid: ceil(N_EDGES/4096)
#define EPB 4096           // edges per block in binA/binC
#define DCAP 6144          // per-bucket capacity
#define NTILES 6250        // N_NODES / 16

typedef __attribute__((ext_vector_type(8))) short bf16x8;
typedef __attribute__((ext_vector_type(4))) float f32x4;

// ---------------- bf16 helpers ----------------
__device__ __forceinline__ unsigned short f2bf(float f) {
    unsigned int i = __float_as_uint(f);
    i += 0x7FFFu + ((i >> 16) & 1u);   // RNE
    return (unsigned short)(i >> 16);
}
// fma 8 bf16 channels packed in uint4 into a[0..7]
__device__ __forceinline__ void fma8(float* a, uint4 v, float wv) {
    a[0] = fmaf(wv, __uint_as_float(v.x << 16), a[0]);
    a[1] = fmaf(wv, __uint_as_float(v.x & 0xFFFF0000u), a[1]);
    a[2] = fmaf(wv, __uint_as_float(v.y << 16), a[2]);
    a[3] = fmaf(wv, __uint_as_float(v.y & 0xFFFF0000u), a[3]);
    a[4] = fmaf(wv, __uint_as_float(v.z << 16), a[4]);
    a[5] = fmaf(wv, __uint_as_float(v.z & 0xFFFF0000u), a[5]);
    a[6] = fmaf(wv, __uint_as_float(v.w << 16), a[6]);
    a[7] = fmaf(wv, __uint_as_float(v.w & 0xFFFF0000u), a[7]);
}

// ---------------- radix-binned CSR build (no global atomics) ----------------

__global__ void binA(const int* __restrict__ col, int* __restrict__ histT) {
    __shared__ int h[NBUCK];
    int t = threadIdx.x;
    for (int i = t; i < NBUCK; i += 256) h[i] = 0;
    __syncthreads();
    int e0 = blockIdx.x * EPB;
    for (int i = t; i < EPB; i += 256) {
        int e = e0 + i;
        if (e < N_EDGES) atomicAdd(&h[col[e] >> 8], 1);
    }
    __syncthreads();
    for (int i = t; i < NBUCK; i += 256) histT[i * GBE + blockIdx.x] = h[i];
}

__global__ void binB1(int* __restrict__ histT, int* __restrict__ rowtot) {
    if (threadIdx.x != 0) return;
    int b = blockIdx.x;
    int acc = 0;
    for (int j = 0; j < GBE; ++j) {
        int v = histT[b * GBE + j];
        histT[b * GBE + j] = acc;
        acc += v;
    }
    rowtot[b] = acc;
}

__global__ void binB2(const int* __restrict__ rowtot, int* __restrict__ bucketOff) {
    if (threadIdx.x != 0) return;
    int acc = 0;
    for (int b = 0; b < NBUCK; ++b) { bucketOff[b] = acc; acc += rowtot[b]; }
    bucketOff[NBUCK] = acc;   // == N_EDGES
}

__global__ void binC(const int* __restrict__ row, const int* __restrict__ col,
                     const float* __restrict__ w, const int* __restrict__ histT,
                     const int* __restrict__ bucketOff, int2* __restrict__ part_sw,
                     unsigned char* __restrict__ part_dlo) {
    __shared__ int cur[NBUCK];
    int t = threadIdx.x;
    for (int i = t; i < NBUCK; i += 256)
        cur[i] = bucketOff[i] + histT[i * GBE + blockIdx.x];
    __syncthreads();
    int e0 = blockIdx.x * EPB;
    for (int i = t; i < EPB; i += 256) {
        int e = e0 + i;
        if (e >= N_EDGES) continue;
        int c = col[e];
        int pos = atomicAdd(&cur[c >> 8], 1);       // LDS atomic
        int2 p; p.x = row[e]; p.y = __float_as_int(w[e]);
        part_sw[pos] = p;
        part_dlo[pos] = (unsigned char)(c & 255);
    }
}

// D: per-bucket CSR in LDS; emits epack + base + dinv (fused weighted degree)
__global__ void binD(const int2* __restrict__ part_sw, const unsigned char* __restrict__ part_dlo,
                     const int* __restrict__ bucketOff, int2* __restrict__ epack,
                     int* __restrict__ base, float* __restrict__ dinv) {
    __shared__ unsigned short dlo[DCAP];
    __shared__ int hist[257];
    __shared__ int cur[256];
    __shared__ float wsum[256];
    int b = blockIdx.x, t = threadIdx.x;
    int s0 = bucketOff[b], m = bucketOff[b + 1] - s0;
    for (int i = t; i < 257; i += 256) hist[i] = 0;
    wsum[t] = 0.0f;
    __syncthreads();
    for (int i = t; i < m; i += 256) {
        int dl = part_dlo[s0 + i];
        dlo[i] = (unsigned short)dl;
        atomicAdd(&hist[dl], 1);
    }
    __syncthreads();
    if (t == 0) {
        int acc = 0;
        for (int i = 0; i < 256; ++i) { int v = hist[i]; hist[i] = acc; acc += v; }
        hist[256] = acc;
    }
    __syncthreads();
    cur[t] = hist[t];
    int dst = b * 256 + t;
    if (dst < N_NODES) base[dst] = s0 + hist[t];
    if (b == NBUCK - 1 && t == 0) base[N_NODES] = N_EDGES;
    __syncthreads();
    for (int i = t; i < m; i += 256) {
        int dl = dlo[i];
        int2 p = part_sw[s0 + i];
        int pos = s0 + atomicAdd(&cur[dl], 1);      // LDS atomic
        epack[pos] = p;
        atomicAdd(&wsum[dl], __int_as_float(p.y));  // LDS float atomic
    }
    __syncthreads();
    if (dst < N_NODES) dinv[dst] = rsqrtf(1.0f + wsum[t]);
}

// xsb[i][d] = bf16(dinv[i] * x[i][d])
__global__ void prescale_bf16(const float4* __restrict__ in4, const float* __restrict__ dinv,
                              ushort4* __restrict__ out4) {
    int gid = blockIdx.x * 256 + threadIdx.x;
    if (gid >= N_NODES * (D / 4)) return;
    float s = dinv[gid >> 4];
    float4 v = in4[gid];
    ushort4 o;
    o.x = f2bf(s * v.x); o.y = f2bf(s * v.y);
    o.z = f2bf(s * v.z); o.w = f2bf(s * v.w);
    out4[gid] = o;
}

// ---------------- fused layer (interleaved agg + MFMA + coalesced LDS-staged write) --
// Block = one 16-node tile (output tile is CONTIGUOUS 4KB in global). Wave w
// aggregates nodes 4w..4w+3 as 2 interleaved pairs; MFMA computes T@W; results
// staged in LDS To[16][68] f32, then one linear coalesced store pass.
template <bool LAST>
__global__ __launch_bounds__(256, 8)
void gcn_layer(const unsigned short* __restrict__ xsb, const float* __restrict__ W,
               const float* __restrict__ b, const float* __restrict__ dinv,
               const int2* __restrict__ epack, const int* __restrict__ base,
               unsigned short* __restrict__ hb_out, float* __restrict__ f_out) {
    __shared__ unsigned short T[16 * 72];    // agg rows bf16, row-padded
    __shared__ float To[16 * 68];            // output staging f32, row-padded
    int t = threadIdx.x;
    int lane  = t & 63;
    int wid   = t >> 6;
    int g     = lane >> 3;               // edge slot 0..7
    int c8    = (lane & 7) * 8;          // channel octet
    int r16   = lane & 15;
    int halfk = (lane >> 4) * 8;         // k offset within K=32 chunk

    // B fragments direct from global W (issued now, consumed at the end)
    int bcol = wid * 16 + r16;
    bf16x8 bf0, bf1;
#pragma unroll
    for (int i = 0; i < 8; ++i) bf0[i] = (short)f2bf(W[(halfk + i) * D + bcol]);
#pragma unroll
    for (int i = 0; i < 8; ++i) bf1[i] = (short)f2bf(W[(halfk + 32 + i) * D + bcol]);
    float bias = b[bcol];

    int node0 = blockIdx.x * 16;
    // ---- aggregate this wave's 4 nodes, as 2 interleaved pairs ----
    for (int jp = 0; jp < 2; ++jp) {
        int nA = node0 + wid * 4 + jp * 2;
        int nB = nA + 1;
        float aA[8], aB[8];
#pragma unroll
        for (int q = 0; q < 8; ++q) { aA[q] = 0.0f; aB[q] = 0.0f; }
        if (g == 0) {                        // self term A (prescaled, w=1)
            uint4 sv = *(const uint4*)(xsb + (size_t)nA * D + c8);
            fma8(aA, sv, 1.0f);
        }
        if (g == 1) {                        // self term B
            uint4 sv = *(const uint4*)(xsb + (size_t)nB * D + c8);
            fma8(aB, sv, 1.0f);
        }
        int kA = base[nA], enA = base[nA + 1];
        int kB = enA,      enB = base[nB + 1];   // CSR rows are contiguous
        while (kA < enA || kB < enB) {
            uint4 vA, vB;
            float wA = 0.0f, wB = 0.0f;
            bool doA = kA < enA, doB = kB < enB;
            if (doA) {
                int kg = kA + g;
                int kc = (kg < enA) ? kg : (enA - 1);
                int2 p = epack[kc];
                wA = (kg < enA) ? __int_as_float(p.y) : 0.0f;
                vA = *(const uint4*)(xsb + (size_t)p.x * D + c8);   // chain 1
            }
            if (doB) {
                int kg = kB + g;
                int kc = (kg < enB) ? kg : (enB - 1);
                int2 p = epack[kc];
                wB = (kg < enB) ? __int_as_float(p.y) : 0.0f;
                vB = *(const uint4*)(xsb + (size_t)p.x * D + c8);   // chain 2
            }
            if (doA) fma8(aA, vA, wA);
            if (doB) fma8(aB, vB, wB);
            kA += 8; kB += 8;
        }
#pragma unroll
        for (int q = 0; q < 8; ++q) {        // fold 8 edge-slot groups (both nodes)
            aA[q] += __shfl_xor(aA[q], 8);
            aB[q] += __shfl_xor(aB[q], 8);
            aA[q] += __shfl_xor(aA[q], 16);
            aB[q] += __shfl_xor(aB[q], 16);
            aA[q] += __shfl_xor(aA[q], 32);
            aB[q] += __shfl_xor(aB[q], 32);
        }
        // pack rows to bf16, park in LDS: lanes 0-7 -> row A, lanes 8-15 -> row B
        if (lane < 16) {
            float* a = (lane < 8) ? aA : aB;
            int nl = wid * 4 + jp * 2 + (lane >> 3);
            int l8 = (lane & 7) * 8;
            uint4 pk;
            pk.x = ((unsigned)f2bf(a[1]) << 16) | f2bf(a[0]);
            pk.y = ((unsigned)f2bf(a[3]) << 16) | f2bf(a[2]);
            pk.z = ((unsigned)f2bf(a[5]) << 16) | f2bf(a[4]);
            pk.w = ((unsigned)f2bf(a[7]) << 16) | f2bf(a[6]);
            *(uint4*)&T[nl * 72 + l8] = pk;
        }
    }
    __syncthreads();                         // T tile complete
    // ---- MFMA: 16 nodes x 16 cols, K=64 in two chunks ----
    bf16x8 af0 = *(const bf16x8*)&T[r16 * 72 + halfk];
    bf16x8 af1 = *(const bf16x8*)&T[r16 * 72 + halfk + 32];
    f32x4 acc = {0.f, 0.f, 0.f, 0.f};
    acc = __builtin_amdgcn_mfma_f32_16x16x32_bf16(af0, bf0, acc, 0, 0, 0);
    acc = __builtin_amdgcn_mfma_f32_16x16x32_bf16(af1, bf1, acc, 0, 0, 0);
    // stage results in LDS (2-way bank alias only)
#pragma unroll
    for (int i = 0; i < 4; ++i) {
        int nr = (lane >> 4) * 4 + i;
        float s = dinv[node0 + nr];
        float y = fmaxf(fmaf(s, acc[i], bias), 0.0f);
        To[nr * 68 + bcol] = LAST ? y : s * y;   // prescale for next layer
    }
    __syncthreads();
    // ---- coalesced contiguous tile store: elements node0*D + [0,1024) ----
    {
        int r = t >> 4, c = (t & 15) * 4;
        float4 v = *(const float4*)&To[r * 68 + c];
        if (LAST) {
            *(float4*)&f_out[(size_t)node0 * D + t * 4] = v;
        } else {
            uint2 pk;
            pk.x = ((unsigned)f2bf(v.y) << 16) | f2bf(v.x);
            pk.y = ((unsigned)f2bf(v.w) << 16) | f2bf(v.z);
            *(uint2*)&hb_out[(size_t)node0 * D + t * 4] = pk;
        }
    }
}

extern "C" void kernel_launch(void* const* d_in, const int* in_sizes, int n_in,
                              void* d_out, int out_size, void* d_ws, size_t ws_size,
                              hipStream_t stream) {
    const float* x       = (const float*)d_in[0];
    const int*   adj     = (const int*)d_in[1];    // [2][E]
    const float* adj_wts = (const float*)d_in[2];
    const float* W1      = (const float*)d_in[3];
    const float* b1      = (const float*)d_in[4];
    const float* W2      = (const float*)d_in[5];
    const float* b2      = (const float*)d_in[6];
    float* out = (float*)d_out;

    const int* row = adj;
    const int* col = adj + N_EDGES;

    // workspace layout (every block 16B-aligned)
    char* p = (char*)d_ws;
    int2* epack = (int2*)p;                   p += (size_t)N_EDGES * 8;       // 12.8MB
    unsigned short* xsb = (unsigned short*)p; p += (size_t)N_NODES * D * 2;   // 12.8MB
    unsigned short* hb  = (unsigned short*)p; p += (size_t)N_NODES * D * 2;   // 12.8MB
    int2* part_sw = (int2*)p;                 p += (size_t)N_EDGES * 8;       // 12.8MB
    unsigned char* part_dlo = (unsigned char*)p; p += N_EDGES;                // 1.6MB
    int* histT = (int*)p;                     p += (size_t)(NBUCK * GBE + 3) / 4 * 4 * 4;
    int* rowtot = (int*)p;                    p += 392 * 4;
    int* bucketOff = (int*)p;                 p += 392 * 4;
    int* base = (int*)p;                      p += 100004 * 4;
    float* dinv = (float*)p;                  p += 100000 * 4;

    const int nblk_c = (N_NODES * 16 + 255) / 256;

    // ---- CSR build: LDS-binned radix partition, zero global atomics ----
    binA<<<GBE, 256, 0, stream>>>(col, histT);
    binB1<<<NBUCK, 64, 0, stream>>>(histT, rowtot);
    binB2<<<1, 64, 0, stream>>>(rowtot, bucketOff);
    binC<<<GBE, 256, 0, stream>>>(row, col, adj_wts, histT, bucketOff, part_sw, part_dlo);
    binD<<<NBUCK, 256, 0, stream>>>(part_sw, part_dlo, bucketOff, epack, base, dinv);

    // ---- x -> dinv-prescaled bf16 ----
    prescale_bf16<<<nblk_c, 256, 0, stream>>>((const float4*)x, dinv, (ushort4*)xsb);

    // ---- fused layers (interleaved gather agg + MFMA + coalesced writes) ----
    gcn_layer<false><<<NTILES, 256, 0, stream>>>(xsb, W1, b1, dinv, epack, base, hb, nullptr);
    gcn_layer<true ><<<NTILES, 256, 0, stream>>>(hb, W2, b2, dinv, epack, base, nullptr, out);
}

// Round 11
// 198.819 us; speedup vs baseline: 1.1670x; 1.1670x over previous
//
#include <hip/hip_runtime.h>

#define N_NODES 100000
#define N_EDGES 1600000
#define D 64
#define NBUCK 391          // ceil(N_NODES/256) buckets of 256 dst
#define GBE 391            // edge-pass grid: ceil(N_EDGES/4096)
#define EPB 4096           // edges per block in binA/binC
#define DCAP 6144          // per-bucket capacity
#define NTILES 6250        // N_NODES / 16

typedef __attribute__((ext_vector_type(8))) short bf16x8;
typedef __attribute__((ext_vector_type(4))) float f32x4;

// ---------------- bf16 helpers ----------------
__device__ __forceinline__ unsigned short f2bf(float f) {
    unsigned int i = __float_as_uint(f);
    i += 0x7FFFu + ((i >> 16) & 1u);   // RNE
    return (unsigned short)(i >> 16);
}
// fma 8 bf16 channels packed in uint4 into a[0..7]
__device__ __forceinline__ void fma8(float* a, uint4 v, float wv) {
    a[0] = fmaf(wv, __uint_as_float(v.x << 16), a[0]);
    a[1] = fmaf(wv, __uint_as_float(v.x & 0xFFFF0000u), a[1]);
    a[2] = fmaf(wv, __uint_as_float(v.y << 16), a[2]);
    a[3] = fmaf(wv, __uint_as_float(v.y & 0xFFFF0000u), a[3]);
    a[4] = fmaf(wv, __uint_as_float(v.z << 16), a[4]);
    a[5] = fmaf(wv, __uint_as_float(v.z & 0xFFFF0000u), a[5]);
    a[6] = fmaf(wv, __uint_as_float(v.w << 16), a[6]);
    a[7] = fmaf(wv, __uint_as_float(v.w & 0xFFFF0000u), a[7]);
}

// ---------------- radix-binned CSR build (no global atomics) ----------------

__global__ void binA(const int* __restrict__ col, int* __restrict__ histT) {
    __shared__ int h[NBUCK];
    int t = threadIdx.x;
    for (int i = t; i < NBUCK; i += 256) h[i] = 0;
    __syncthreads();
    int e0 = blockIdx.x * EPB;
    for (int i = t; i < EPB; i += 256) {
        int e = e0 + i;
        if (e < N_EDGES) atomicAdd(&h[col[e] >> 8], 1);
    }
    __syncthreads();
    for (int i = t; i < NBUCK; i += 256) histT[i * GBE + blockIdx.x] = h[i];
}

// B1: PARALLEL exclusive scan of each bucket-row across blocks (512-thread H-S)
__global__ void binB1(int* __restrict__ histT, int* __restrict__ rowtot) {
    __shared__ int s[512];
    int b = blockIdx.x, tid = threadIdx.x;
    int v = (tid < GBE) ? histT[b * GBE + tid] : 0;
    s[tid] = v;
    __syncthreads();
    for (int o = 1; o < 512; o <<= 1) {
        int t = (tid >= o) ? s[tid - o] : 0;
        __syncthreads();
        s[tid] += t;
        __syncthreads();
    }
    if (tid < GBE) histT[b * GBE + tid] = s[tid] - v;   // exclusive
    if (tid == 511) rowtot[b] = s[511];
}

// B2: PARALLEL exclusive scan of rowtot -> bucketOff (single 512-thread block)
__global__ void binB2(const int* __restrict__ rowtot, int* __restrict__ bucketOff) {
    __shared__ int s[512];
    int tid = threadIdx.x;
    int v = (tid < NBUCK) ? rowtot[tid] : 0;
    s[tid] = v;
    __syncthreads();
    for (int o = 1; o < 512; o <<= 1) {
        int t = (tid >= o) ? s[tid - o] : 0;
        __syncthreads();
        s[tid] += t;
        __syncthreads();
    }
    if (tid < NBUCK) bucketOff[tid] = s[tid] - v;       // exclusive
    if (tid == 0) bucketOff[NBUCK] = N_EDGES;
}

__global__ void binC(const int* __restrict__ row, const int* __restrict__ col,
                     const float* __restrict__ w, const int* __restrict__ histT,
                     const int* __restrict__ bucketOff, int2* __restrict__ part_sw,
                     unsigned char* __restrict__ part_dlo) {
    __shared__ int cur[NBUCK];
    int t = threadIdx.x;
    for (int i = t; i < NBUCK; i += 256)
        cur[i] = bucketOff[i] + histT[i * GBE + blockIdx.x];
    __syncthreads();
    int e0 = blockIdx.x * EPB;
    for (int i = t; i < EPB; i += 256) {
        int e = e0 + i;
        if (e >= N_EDGES) continue;
        int c = col[e];
        int pos = atomicAdd(&cur[c >> 8], 1);       // LDS atomic
        int2 p; p.x = row[e]; p.y = __float_as_int(w[e]);
        part_sw[pos] = p;
        part_dlo[pos] = (unsigned char)(c & 255);
    }
}

// D: per-bucket CSR in LDS; emits epack + base + dinv (fused weighted degree)
__global__ void binD(const int2* __restrict__ part_sw, const unsigned char* __restrict__ part_dlo,
                     const int* __restrict__ bucketOff, int2* __restrict__ epack,
                     int* __restrict__ base, float* __restrict__ dinv) {
    __shared__ unsigned short dlo[DCAP];
    __shared__ int hist[257];
    __shared__ int cur[256];
    __shared__ float wsum[256];
    int b = blockIdx.x, t = threadIdx.x;
    int s0 = bucketOff[b], m = bucketOff[b + 1] - s0;
    for (int i = t; i < 257; i += 256) hist[i] = 0;
    wsum[t] = 0.0f;
    __syncthreads();
    for (int i = t; i < m; i += 256) {
        int dl = part_dlo[s0 + i];
        dlo[i] = (unsigned short)dl;
        atomicAdd(&hist[dl], 1);
    }
    __syncthreads();
    if (t == 0) {
        int acc = 0;
        for (int i = 0; i < 256; ++i) { int v = hist[i]; hist[i] = acc; acc += v; }
        hist[256] = acc;
    }
    __syncthreads();
    cur[t] = hist[t];
    int dst = b * 256 + t;
    if (dst < N_NODES) base[dst] = s0 + hist[t];
    if (b == NBUCK - 1 && t == 0) base[N_NODES] = N_EDGES;
    __syncthreads();
    for (int i = t; i < m; i += 256) {
        int dl = dlo[i];
        int2 p = part_sw[s0 + i];
        int pos = s0 + atomicAdd(&cur[dl], 1);      // LDS atomic
        epack[pos] = p;
        atomicAdd(&wsum[dl], __int_as_float(p.y));  // LDS float atomic
    }
    __syncthreads();
    if (dst < N_NODES) dinv[dst] = rsqrtf(1.0f + wsum[t]);
}

// xsb[i][d] = bf16(dinv[i] * x[i][d])
__global__ void prescale_bf16(const float4* __restrict__ in4, const float* __restrict__ dinv,
                              ushort4* __restrict__ out4) {
    int gid = blockIdx.x * 256 + threadIdx.x;
    if (gid >= N_NODES * (D / 4)) return;
    float s = dinv[gid >> 4];
    float4 v = in4[gid];
    ushort4 o;
    o.x = f2bf(s * v.x); o.y = f2bf(s * v.y);
    o.z = f2bf(s * v.z); o.w = f2bf(s * v.w);
    out4[gid] = o;
}

// ---------------- fused layer (r9 structure, 4 blocks/CU) ----------------
// Block = one 16-node tile, 4 waves. Wave w aggregates nodes 4w..4w+3 as TWO
// interleaved pairs (2 gather chains in flight); MFMA epilogue computes T@W.
// launch_bounds(256,4): cap 4 blocks/CU — r8-vs-r9 evidence says the L2 fetch/
// write amplification (125/87.5 MB vs 88/12.5 MB) is occupancy-driven thrash.
template <bool LAST>
__global__ __launch_bounds__(256, 4)
void gcn_layer(const unsigned short* __restrict__ xsb, const float* __restrict__ W,
               const float* __restrict__ b, const float* __restrict__ dinv,
               const int2* __restrict__ epack, const int* __restrict__ base,
               unsigned short* __restrict__ hb_out, float* __restrict__ f_out) {
    __shared__ unsigned short T[16 * 72];       // agg rows bf16, row-padded
    int t = threadIdx.x;
    int lane  = t & 63;
    int wid   = t >> 6;
    int g     = lane >> 3;               // edge slot 0..7
    int c8    = (lane & 7) * 8;          // channel octet
    int r16   = lane & 15;
    int halfk = (lane >> 4) * 8;         // k offset within K=32 chunk

    // B fragments direct from global W (issued now, consumed at the end)
    int bcol = wid * 16 + r16;
    bf16x8 bf0, bf1;
#pragma unroll
    for (int i = 0; i < 8; ++i) bf0[i] = (short)f2bf(W[(halfk + i) * D + bcol]);
#pragma unroll
    for (int i = 0; i < 8; ++i) bf1[i] = (short)f2bf(W[(halfk + 32 + i) * D + bcol]);
    float bias = b[bcol];

    int node0 = blockIdx.x * 16;
    // ---- aggregate this wave's 4 nodes, as 2 interleaved pairs ----
    for (int jp = 0; jp < 2; ++jp) {
        int nA = node0 + wid * 4 + jp * 2;
        int nB = nA + 1;
        float aA[8], aB[8];
#pragma unroll
        for (int q = 0; q < 8; ++q) { aA[q] = 0.0f; aB[q] = 0.0f; }
        if (g == 0) {                        // self term A (prescaled, w=1)
            uint4 sv = *(const uint4*)(xsb + (size_t)nA * D + c8);
            fma8(aA, sv, 1.0f);
        }
        if (g == 1) {                        // self term B
            uint4 sv = *(const uint4*)(xsb + (size_t)nB * D + c8);
            fma8(aB, sv, 1.0f);
        }
        int kA = base[nA], enA = base[nA + 1];
        int kB = enA,      enB = base[nB + 1];   // CSR rows are contiguous
        while (kA < enA || kB < enB) {
            uint4 vA, vB;
            float wA = 0.0f, wB = 0.0f;
            bool doA = kA < enA, doB = kB < enB;
            if (doA) {
                int kg = kA + g;
                int kc = (kg < enA) ? kg : (enA - 1);
                int2 p = epack[kc];
                wA = (kg < enA) ? __int_as_float(p.y) : 0.0f;
                vA = *(const uint4*)(xsb + (size_t)p.x * D + c8);   // chain 1
            }
            if (doB) {
                int kg = kB + g;
                int kc = (kg < enB) ? kg : (enB - 1);
                int2 p = epack[kc];
                wB = (kg < enB) ? __int_as_float(p.y) : 0.0f;
                vB = *(const uint4*)(xsb + (size_t)p.x * D + c8);   // chain 2
            }
            if (doA) fma8(aA, vA, wA);
            if (doB) fma8(aB, vB, wB);
            kA += 8; kB += 8;
        }
#pragma unroll
        for (int q = 0; q < 8; ++q) {        // fold 8 edge-slot groups (both nodes)
            aA[q] += __shfl_xor(aA[q], 8);
            aB[q] += __shfl_xor(aB[q], 8);
            aA[q] += __shfl_xor(aA[q], 16);
            aB[q] += __shfl_xor(aB[q], 16);
            aA[q] += __shfl_xor(aA[q], 32);
            aB[q] += __shfl_xor(aB[q], 32);
        }
        // pack rows to bf16, park in LDS: lanes 0-7 -> row A, lanes 8-15 -> row B
        if (lane < 16) {
            float* a = (lane < 8) ? aA : aB;
            int nl = wid * 4 + jp * 2 + (lane >> 3);
            int l8 = (lane & 7) * 8;
            uint4 pk;
            pk.x = ((unsigned)f2bf(a[1]) << 16) | f2bf(a[0]);
            pk.y = ((unsigned)f2bf(a[3]) << 16) | f2bf(a[2]);
            pk.z = ((unsigned)f2bf(a[5]) << 16) | f2bf(a[4]);
            pk.w = ((unsigned)f2bf(a[7]) << 16) | f2bf(a[6]);
            *(uint4*)&T[nl * 72 + l8] = pk;
        }
    }
    __syncthreads();                         // T tile complete
    // ---- MFMA: 16 nodes x 16 cols, K=64 in two chunks ----
    bf16x8 af0 = *(const bf16x8*)&T[r16 * 72 + halfk];
    bf16x8 af1 = *(const bf16x8*)&T[r16 * 72 + halfk + 32];
    f32x4 acc = {0.f, 0.f, 0.f, 0.f};
    acc = __builtin_amdgcn_mfma_f32_16x16x32_bf16(af0, bf0, acc, 0, 0, 0);
    acc = __builtin_amdgcn_mfma_f32_16x16x32_bf16(af1, bf1, acc, 0, 0, 0);
#pragma unroll
    for (int i = 0; i < 4; ++i) {
        int nr = (lane >> 4) * 4 + i;
        int node = node0 + nr;
        float s = dinv[node];
        float y = fmaxf(fmaf(s, acc[i], bias), 0.0f);
        size_t oidx = (size_t)node * D + bcol;
        if (LAST) f_out[oidx] = y;
        else      hb_out[oidx] = f2bf(s * y);   // prescale for next layer
    }
}

extern "C" void kernel_launch(void* const* d_in, const int* in_sizes, int n_in,
                              void* d_out, int out_size, void* d_ws, size_t ws_size,
                              hipStream_t stream) {
    const float* x       = (const float*)d_in[0];
    const int*   adj     = (const int*)d_in[1];    // [2][E]
    const float* adj_wts = (const float*)d_in[2];
    const float* W1      = (const float*)d_in[3];
    const float* b1      = (const float*)d_in[4];
    const float* W2      = (const float*)d_in[5];
    const float* b2      = (const float*)d_in[6];
    float* out = (float*)d_out;

    const int* row = adj;
    const int* col = adj + N_EDGES;

    // workspace layout (every block 16B-aligned)
    char* p = (char*)d_ws;
    int2* epack = (int2*)p;                   p += (size_t)N_EDGES * 8;       // 12.8MB
    unsigned short* xsb = (unsigned short*)p; p += (size_t)N_NODES * D * 2;   // 12.8MB
    unsigned short* hb  = (unsigned short*)p; p += (size_t)N_NODES * D * 2;   // 12.8MB
    int2* part_sw = (int2*)p;                 p += (size_t)N_EDGES * 8;       // 12.8MB
    unsigned char* part_dlo = (unsigned char*)p; p += N_EDGES;                // 1.6MB
    int* histT = (int*)p;                     p += (size_t)(NBUCK * GBE + 3) / 4 * 4 * 4;
    int* rowtot = (int*)p;                    p += 392 * 4;
    int* bucketOff = (int*)p;                 p += 392 * 4;
    int* base = (int*)p;                      p += 100004 * 4;
    float* dinv = (float*)p;                  p += 100000 * 4;

    const int nblk_c = (N_NODES * 16 + 255) / 256;

    // ---- CSR build: LDS-binned radix partition, zero global atomics ----
    binA<<<GBE, 256, 0, stream>>>(col, histT);
    binB1<<<NBUCK, 512, 0, stream>>>(histT, rowtot);
    binB2<<<1, 512, 0, stream>>>(rowtot, bucketOff);
    binC<<<GBE, 256, 0, stream>>>(row, col, adj_wts, histT, bucketOff, part_sw, part_dlo);
    binD<<<NBUCK, 256, 0, stream>>>(part_sw, part_dlo, bucketOff, epack, base, dinv);

    // ---- x -> dinv-prescaled bf16 ----
    prescale_bf16<<<nblk_c, 256, 0, stream>>>((const float4*)x, dinv, (ushort4*)xsb);

    // ---- fused layers (interleaved gather agg + MFMA GEMM) ----
    gcn_layer<false><<<NTILES, 256, 0, stream>>>(xsb, W1, b1, dinv, epack, base, hb, nullptr);
    gcn_layer<true ><<<NTILES, 256, 0, stream>>>(hb, W2, b2, dinv, epack, base, nullptr, out);
}